// Round 3
// baseline (889.164 us; speedup 1.0000x reference)
//
#include <hip/hip_runtime.h>
#include <hip/hip_bf16.h>

// ComplexAttentivePooling: B=16,S=8192,D=512,H=8,K=V=64
// Restructure: score[b,s,h] = (x.u_h + c_h)/||q|| ; pooled = (sum_s sc*x_s)@Wv + (sum sc)*bv
// -> only qr,qi projections via bf16 MFMA (137 GFLOP), y-accumulation, tiny finish GEMM.
//
// R1 fix: mask is a bool array staged as INTEGER (int32, 4B/elem) per harness
// convention ("integer -> const int*"). Reading it as bytes kept only s%4==0
// tokens (error 20.78 ~= 0.75 * signal max 26.75). Now read as const int*.
// R2: unchanged resubmit — R1 run died on GPUAcquisitionTimeout (no data).

#define CB 16
#define CS 8192
#define CD 512
#define CH 8
#define CK 64
#define NCOL 128          // 2*K (real|imag) per head
#define TM 64             // tokens per block
#define EPSV 1e-12f

typedef __attribute__((ext_vector_type(8))) unsigned short us8;
typedef __attribute__((ext_vector_type(8))) __bf16 bf16x8;
typedef __attribute__((ext_vector_type(4))) float f32x4;

__device__ __forceinline__ unsigned short f2bf(float f) {
  __hip_bfloat16 h = __float2bfloat16(f);
  return *reinterpret_cast<unsigned short*>(&h);
}
__device__ __forceinline__ float bf2f(unsigned short u) {
  unsigned int x = ((unsigned int)u) << 16;
  return __uint_as_float(x);
}
__device__ __forceinline__ bf16x8 as_bf(us8 u) { return __builtin_bit_cast(bf16x8, u); }

// ---------------- prep: build bf16 W^T [1024 cols][512 k], wvec, bqc ----------------
__global__ void cap_prep(const float* __restrict__ Wq_r, const float* __restrict__ Wq_i,
                         const float* __restrict__ key_real, const float* __restrict__ key_imag,
                         const float* __restrict__ bq_r, const float* __restrict__ bq_i,
                         unsigned short* __restrict__ wbt, float* __restrict__ wvec,
                         float* __restrict__ bqc) {
  int blk = blockIdx.x, tid = threadIdx.x;
  if (blk < CH * NCOL) {  // 1024 transpose blocks: one output column each
    int h = blk >> 7, c = blk & 127;
    const float* src = (c < CK) ? (Wq_r + (size_t)h * CD * CK + c)
                                : (Wq_i + (size_t)h * CD * CK + (c - CK));
    for (int d = tid; d < CD; d += 256)
      wbt[(size_t)blk * CD + d] = f2bf(src[(size_t)d * CK]);
  } else {  // 8 key blocks
    int h = blk - CH * NCOL;
    __shared__ float knsh;
    if (tid < 64) {
      float a = key_real[h * CK + tid], b = key_imag[h * CK + tid];
      float t = a * a + b * b;
      #pragma unroll
      for (int off = 1; off < 64; off <<= 1) t += __shfl_xor(t, off);
      if (tid == 0) knsh = sqrtf(fmaxf(t, EPSV));
    }
    __syncthreads();
    if (tid < NCOL) {
      int c = tid;
      float kn = knsh;
      wvec[h * NCOL + c] = (c < CK) ? key_real[h * CK + c] / kn
                                    : -key_imag[h * CK + (c - CK)] / kn;
      bqc[h * NCOL + c] = (c < CK) ? bq_r[h * CK + c] : bq_i[h * CK + (c - CK)];
    }
  }
}

// ---------------- main fused kernel ----------------
// grid 2048 (16 batches x 128 s-tiles), 512 threads (8 waves), dyn LDS 134144 B
#define XL_BYTES (TM * CD * 2)              // 65536
#define WL_BYTES (NCOL * 256 * 2)           // 65536, W chunk [128 cols][256 k]
#define SMEM_BYTES (XL_BYTES + WL_BYTES + 512 + 512 + 2048)

__global__ __launch_bounds__(512, 2) void cap_main(
    const float* __restrict__ x, const int* __restrict__ mask,
    const unsigned short* __restrict__ wbt, const float* __restrict__ wvec,
    const float* __restrict__ bqc, float* __restrict__ yws, float* __restrict__ ssum) {
  extern __shared__ char smem[];
  char* Xl = smem;                       // [64 rows][1024 B] swizzled bf16
  char* Wl = smem + XL_BYTES;            // [128 cols][512 B] swizzled bf16
  float* partn = (float*)(smem + XL_BYTES + WL_BYTES);   // [2][64]
  float* partm = partn + 128;                            // [2][64]
  float* scoresA = partm + 128;                          // [8][64]

  const int tid = threadIdx.x;
  const int w = tid >> 6, l = tid & 63;
  const int blk = blockIdx.x;
  const int b = blk >> 7;
  const int s0 = (blk & 127) * TM;
  const float* xrow = x + ((size_t)(b * CS + s0)) * CD;

  // ---- stage X tile: f32 -> bf16, XOR-swizzled rows (G4: break the 1024B-stride conflict)
  #pragma unroll
  for (int i = 0; i < 8; ++i) {
    int id = i * 512 + tid;
    int row = id >> 6, cc = id & 63;                 // cc = 8-elem chunk in row
    const float* src = xrow + row * CD + cc * 8;
    float4 f0 = *(const float4*)(src);
    float4 f1 = *(const float4*)(src + 4);
    us8 v;
    v[0] = f2bf(f0.x); v[1] = f2bf(f0.y); v[2] = f2bf(f0.z); v[3] = f2bf(f0.w);
    v[4] = f2bf(f1.x); v[5] = f2bf(f1.y); v[6] = f2bf(f1.z); v[7] = f2bf(f1.w);
    int byte = row * 1024 + ((cc * 16) ^ ((row & 7) << 4));
    *(us8*)(Xl + byte) = v;
  }

  const int rw = (w & 3) * 16;    // wave's token-row base
  const int cw = (w >> 2) * 64;   // wave's col base within 128
  const int lr = l & 15;
  const int lk = (l >> 4) * 8;

  #pragma unroll 1
  for (int h = 0; h < CH; ++h) {
    f32x4 acc[4];
    #pragma unroll
    for (int f = 0; f < 4; ++f) acc[f] = (f32x4){0.f, 0.f, 0.f, 0.f};

    #pragma unroll 1
    for (int kc = 0; kc < 2; ++kc) {
      __syncthreads();   // prior readers of Wl done (also covers X staging at h=0,kc=0)
      // stage W chunk: cols h*128..+128, k kc*256..+256
      #pragma unroll
      for (int i = 0; i < 8; ++i) {
        int id = i * 512 + tid;
        int col = id >> 5, kch = id & 31;
        us8 v = *(const us8*)(wbt + (((size_t)(h * NCOL + col)) * CD + kc * 256 + kch * 8));
        int byte = col * 512 + ((kch * 16) ^ ((col & 7) << 4));
        *(us8*)(Wl + byte) = v;
      }
      __syncthreads();
      #pragma unroll
      for (int ks = 0; ks < 8; ++ks) {
        int kloc = ks * 32 + lk;
        int arow = rw + lr;
        int abyte = arow * 1024 + ((((kc * 256 + kloc)) * 2) ^ ((arow & 7) << 4));
        bf16x8 a = as_bf(*(const us8*)(Xl + abyte));
        #pragma unroll
        for (int f = 0; f < 4; ++f) {
          int col = cw + f * 16 + lr;
          int bbyte = col * 512 + ((kloc * 2) ^ ((col & 7) << 4));
          bf16x8 bb = as_bf(*(const us8*)(Wl + bbyte));
          acc[f] = __builtin_amdgcn_mfma_f32_16x16x32_bf16(a, bb, acc[f], 0, 0, 0);
        }
      }
    }

    // ---- epilogue head h: norm^2 and numerator per token row
    float n2[4] = {0.f, 0.f, 0.f, 0.f}, nm[4] = {0.f, 0.f, 0.f, 0.f};
    #pragma unroll
    for (int f = 0; f < 4; ++f) {
      int c = cw + f * 16 + lr;
      float wv = wvec[h * NCOL + c];
      float bq = bqc[h * NCOL + c];
      #pragma unroll
      for (int r = 0; r < 4; ++r) {
        float q = acc[f][r] + bq;     // C layout: col=lane&15, row=(lane>>4)*4+r (m89/m91)
        n2[r] += q * q;
        nm[r] += q * wv;
      }
    }
    #pragma unroll
    for (int off = 1; off < 16; off <<= 1) {
      #pragma unroll
      for (int r = 0; r < 4; ++r) {
        n2[r] += __shfl_xor(n2[r], off);
        nm[r] += __shfl_xor(nm[r], off);
      }
    }
    if (lr == 0) {
      int half = w >> 2;
      #pragma unroll
      for (int r = 0; r < 4; ++r) {
        int row = rw + (l >> 4) * 4 + r;
        partn[half * 64 + row] = n2[r];
        partm[half * 64 + row] = nm[r];
      }
    }
    __syncthreads();
    if (tid < 64) {
      float norm2 = partn[tid] + partn[64 + tid];
      float num = partm[tid] + partm[64 + tid];
      float qn = sqrtf(fmaxf(norm2, EPSV));
      // mask staged as int32 (bool -> integer per harness); robust under both stagings
      float mk = (mask[(size_t)b * CS + s0 + tid] != 0) ? 1.0f : 0.0f;
      float sc = num / qn * mk;
      scoresA[h * 64 + tid] = sc;
      float t = sc;
      #pragma unroll
      for (int off = 1; off < 64; off <<= 1) t += __shfl_xor(t, off);
      if (tid == 0) atomicAdd(&ssum[b * CH + h], t);
    }
  }
  __syncthreads();

  // ---- y pass: y[b,h,d] += sum_row score[h][row] * x_bf16[row][d]
  {
    int d = tid;  // 512 threads = D
    float sreg[CH];
    #pragma unroll
    for (int h = 0; h < CH; ++h) sreg[h] = scoresA[h * 64 + l];
    float yacc[CH];
    #pragma unroll
    for (int h = 0; h < CH; ++h) yacc[h] = 0.f;
    #pragma unroll 4
    for (int row = 0; row < TM; ++row) {
      int byte = row * 1024 + ((d * 2) ^ ((row & 7) << 4));
      float xv = bf2f(*(const unsigned short*)(Xl + byte));
      #pragma unroll
      for (int h = 0; h < CH; ++h) {
        float sc = __uint_as_float(
            __builtin_amdgcn_readlane(__float_as_uint(sreg[h]), row));
        yacc[h] += sc * xv;
      }
    }
    #pragma unroll
    for (int h = 0; h < CH; ++h)
      atomicAdd(&yws[((size_t)b * CH + h) * CD + d], yacc[h]);
  }
}

// ---------------- finish: pooled = y@Wv + ssum*bv ; out = pooled@Wf + bf ----------------
__global__ void cap_finish(const float* __restrict__ yws, const float* __restrict__ ssum,
                           const float* __restrict__ Wv, const float* __restrict__ bv,
                           const float* __restrict__ Wf, const float* __restrict__ bfv,
                           float* __restrict__ out) {
  __shared__ float yl[CH * CD];   // 16 KB
  __shared__ float pl[CH * CK];   // 2 KB (H*V=512)
  __shared__ float ss[CH];
  int b = blockIdx.x, tid = threadIdx.x;
  for (int i = tid; i < CH * CD; i += 256) yl[i] = yws[(size_t)b * CH * CD + i];
  if (tid < CH) ss[tid] = ssum[b * CH + tid];
  __syncthreads();
  #pragma unroll
  for (int jj = 0; jj < 2; ++jj) {
    int j = jj * 256 + tid;
    int h = j >> 6, v = j & 63;
    float acc = ss[h] * bv[h * CK + v];
    const float* yrow = yl + h * CD;
    const float* wcol = Wv + (size_t)h * CD * CK + v;
    #pragma unroll 8
    for (int d = 0; d < CD; ++d) acc += yrow[d] * wcol[(size_t)d * CK];
    pl[j] = acc;
  }
  __syncthreads();
  #pragma unroll
  for (int jj = 0; jj < 2; ++jj) {
    int dout = jj * 256 + tid;
    float o = bfv[dout];
    #pragma unroll 8
    for (int j = 0; j < CH * CK; ++j) o += pl[j] * Wf[(size_t)j * CD + dout];
    out[b * CD + dout] = o;
  }
}

extern "C" void kernel_launch(void* const* d_in, const int* in_sizes, int n_in,
                              void* d_out, int out_size, void* d_ws, size_t ws_size,
                              hipStream_t stream) {
  const float* x = (const float*)d_in[0];
  const int* mask = (const int*)d_in[1];   // bool staged as integer (int32)
  const float* Wq_r = (const float*)d_in[2];
  const float* bq_r = (const float*)d_in[3];
  const float* Wq_i = (const float*)d_in[4];
  const float* bq_i = (const float*)d_in[5];
  const float* Wv = (const float*)d_in[6];
  const float* bv = (const float*)d_in[7];
  const float* key_real = (const float*)d_in[8];
  const float* key_imag = (const float*)d_in[9];
  const float* Wf = (const float*)d_in[10];
  const float* bfv = (const float*)d_in[11];
  float* out = (float*)d_out;

  char* ws = (char*)d_ws;
  unsigned short* wbt = (unsigned short*)ws;                       // 1 MB  bf16 W^T
  float* wvec = (float*)(ws + (1 << 20));                          // 4 KB
  float* bqc = (float*)(ws + (1 << 20) + 4096);                    // 4 KB
  float* yws = (float*)(ws + (1 << 20) + 8192);                    // 256 KB
  float* ssum = (float*)(ws + (1 << 20) + 8192 + CB * CH * CD * 4);  // 512 B

  hipMemsetAsync(yws, 0, CB * CH * CD * 4 + CB * CH * 4, stream);
  cap_prep<<<dim3(CH * NCOL + CH), dim3(256), 0, stream>>>(
      Wq_r, Wq_i, key_real, key_imag, bq_r, bq_i, wbt, wvec, bqc);
  hipFuncSetAttribute((const void*)cap_main,
                      hipFuncAttributeMaxDynamicSharedMemorySize, SMEM_BYTES);
  cap_main<<<dim3(CB * (CS / TM)), dim3(512), SMEM_BYTES, stream>>>(
      x, mask, wbt, wvec, bqc, yws, ssum);
  cap_finish<<<dim3(CB), dim3(256), 0, stream>>>(yws, ssum, Wv, bv, Wf, bfv, out);
}

// Round 4
// 735.089 us; speedup vs baseline: 1.2096x; 1.2096x over previous
//
#include <hip/hip_runtime.h>
#include <hip/hip_bf16.h>

// ComplexAttentivePooling: B=16,S=8192,D=512,H=8,K=V=64
// score[b,s,h] = (x.u_h + c_h)/||q||; pooled = (sum_s sc*x_s)@Wv + (sum sc)*bv.
// R4: restructure cap_main: wave tile 64x64 (4x4 frags, 0.5 ds_reads/MFMA vs 1.25),
//     W dbuf via global_load_lds(16B) 2-phase pipeline, epilogue 2x/block.
//     Parallelized prep/pooled/out kernels (128 blocks each).

#define CB 16
#define CS 8192
#define CD 512
#define CH 8
#define CK 64
#define NCOL 128
#define TM 64
#define EPSV 1e-12f

typedef __attribute__((ext_vector_type(8))) unsigned short us8;
typedef __attribute__((ext_vector_type(8))) __bf16 bf16x8;
typedef __attribute__((ext_vector_type(4))) float f32x4;

__device__ __forceinline__ unsigned short f2bf(float f) {
  __hip_bfloat16 h = __float2bfloat16(f);
  return *reinterpret_cast<unsigned short*>(&h);
}
__device__ __forceinline__ float bf2f(unsigned short u) {
  unsigned int x = ((unsigned int)u) << 16;
  return __uint_as_float(x);
}
__device__ __forceinline__ bf16x8 as_bf(us8 u) { return __builtin_bit_cast(bf16x8, u); }

// async global->LDS, 16B per lane (dest must be base+lane*16 contiguous per wave)
#define G2L16(gp, lp)                                                  \
  __builtin_amdgcn_global_load_lds(                                    \
      (const __attribute__((address_space(1))) unsigned int*)(gp),     \
      (__attribute__((address_space(3))) unsigned int*)(lp), 16, 0, 0)

// ---------------- prep: tiled transpose Wq -> wbt [1024 cols][512 k] bf16 ----------------
// grid 128 = 2(ri) x 8(h) x 8(dtile of 64), 256 threads
__global__ void cap_prep(const float* __restrict__ Wq_r, const float* __restrict__ Wq_i,
                         unsigned short* __restrict__ wbt) {
  __shared__ float tile[64][65];
  int blk = blockIdx.x, t = threadIdx.x;
  int ri = blk >> 6, h = (blk >> 3) & 7, dt = blk & 7;
  const float* src = (ri ? Wq_i : Wq_r) + (size_t)h * CD * CK + (size_t)dt * 64 * CK;
  #pragma unroll
  for (int p = 0; p < 16; ++p) {
    int idx = p * 256 + t;
    int d = idx >> 6, c = idx & 63;
    tile[d][c] = src[(size_t)d * CK + c];   // coalesced over c
  }
  __syncthreads();
  int l = t & 63;
  #pragma unroll
  for (int p = 0; p < 16; ++p) {
    int c = p * 4 + (t >> 6);
    wbt[((size_t)(h * NCOL + ri * 64 + c)) * CD + dt * 64 + l] = f2bf(tile[l][c]);
  }
}

// ---------------- keys: wvec = [kr,-ki]/||key||, bqc = [bq_r,bq_i] ----------------
__global__ void cap_keys(const float* __restrict__ key_real, const float* __restrict__ key_imag,
                         const float* __restrict__ bq_r, const float* __restrict__ bq_i,
                         float* __restrict__ wvec, float* __restrict__ bqc) {
  int h = blockIdx.x, t = threadIdx.x;  // 8 blocks x 128 threads
  __shared__ float kn;
  if (t < 64) {
    float a = key_real[h * CK + t], b2 = key_imag[h * CK + t];
    float s = a * a + b2 * b2;
    #pragma unroll
    for (int off = 1; off < 64; off <<= 1) s += __shfl_xor(s, off);
    if (t == 0) kn = sqrtf(fmaxf(s, EPSV));
  }
  __syncthreads();
  float v = (t < CK) ? key_real[h * CK + t] : -key_imag[h * CK + (t - CK)];
  wvec[h * NCOL + t] = v / kn;
  bqc[h * NCOL + t] = (t < CK) ? bq_r[h * CK + t] : bq_i[h * CK + (t - CK)];
}

// ---------------- main fused kernel ----------------
// grid 2048 (16 b x 128 s-tiles), 512 threads (8 waves).
// LDS: Xl [64 rows][1024B] swizzled | W dbuf 2x32KB [512 cols][64B] linear | scratch
#define XL_BYTES 65536
#define WBUF_BYTES 32768
#define SMEM_BYTES (XL_BYTES + 2 * WBUF_BYTES + 3 * 2048)

__global__ __launch_bounds__(512, 2) void cap_main(
    const float* __restrict__ x, const int* __restrict__ mask,
    const unsigned short* __restrict__ wbt, const float* __restrict__ wvec,
    const float* __restrict__ bqc, float* __restrict__ yws, float* __restrict__ ssum) {
  extern __shared__ char smem[];
  char* Xl = smem;
  char* Wb = smem + XL_BYTES;
  float* partn = (float*)(smem + XL_BYTES + 2 * WBUF_BYTES);  // [8][64]
  float* partm = partn + 512;                                 // [8][64]
  float* scoresA = partm + 512;                               // [8][64]

  const int tid = threadIdx.x;
  const int w = tid >> 6, l = tid & 63;
  const int lr = l & 15, q = l >> 4;
  const int b = blockIdx.x >> 7;
  const int s0 = (blockIdx.x & 127) * TM;
  const float* xrow = x + ((size_t)(b * CS + s0)) * CD;

  // ---- stage W chunk s (s<32): colhalf s>>4, kc s&15 -> buffer s&1 (async)
  auto stageW = [&](int s) {
    if (s >= 32) return;
    int ch = s >> 4, kc = s & 15;
    char* dst = Wb + (size_t)(s & 1) * WBUF_BYTES;
    #pragma unroll
    for (int i = 0; i < 4; ++i) {
      int o = i * 8192 + tid * 16;          // = wave_base + lane*16 (contiguous)
      int col_local = o >> 6;
      int kchunk = (o >> 4) & 3;
      const unsigned short* src =
          wbt + ((size_t)(ch * 512 + col_local)) * CD + kc * 32 + kchunk * 8;
      G2L16(src, dst + o);
    }
  };

  stageW(0);

  // ---- stage X tile: f32 -> bf16, XOR-swizzled (bits 4-6 ^= row&7)
  #pragma unroll
  for (int i = 0; i < 8; ++i) {
    int id = i * 512 + tid;
    int row = id >> 6, cc = id & 63;
    const float* src = xrow + row * CD + cc * 8;
    float4 f0 = *(const float4*)(src);
    float4 f1 = *(const float4*)(src + 4);
    us8 v;
    v[0] = f2bf(f0.x); v[1] = f2bf(f0.y); v[2] = f2bf(f0.z); v[3] = f2bf(f0.w);
    v[4] = f2bf(f1.x); v[5] = f2bf(f1.y); v[6] = f2bf(f1.z); v[7] = f2bf(f1.w);
    int byte = row * 1024 + ((cc * 16) ^ ((row & 7) << 4));
    *(us8*)(Xl + byte) = v;
  }
  __syncthreads();   // drains X ds_writes AND stageW(0) vmem

  #pragma unroll 1
  for (int ch = 0; ch < 2; ++ch) {
    f32x4 acc[4][4];
    #pragma unroll
    for (int m = 0; m < 4; ++m)
      #pragma unroll
      for (int n = 0; n < 4; ++n) acc[m][n] = (f32x4){0.f, 0.f, 0.f, 0.f};

    #pragma unroll 1
    for (int kc = 0; kc < 16; ++kc) {
      int gp = ch * 16 + kc;
      stageW(gp + 1);                       // async prefetch next chunk
      char* wl = Wb + (size_t)(gp & 1) * WBUF_BYTES;
      int kbyte = kc * 64 + q * 16;
      bf16x8 a[4], bb[4];
      #pragma unroll
      for (int m = 0; m < 4; ++m) {
        int row = m * 16 + lr;
        a[m] = as_bf(*(const us8*)(Xl + row * 1024 + (kbyte ^ ((row & 7) << 4))));
      }
      #pragma unroll
      for (int n = 0; n < 4; ++n) {
        int col_local = w * 64 + n * 16 + lr;
        bb[n] = as_bf(*(const us8*)(wl + col_local * 64 + q * 16));
      }
      #pragma unroll
      for (int m = 0; m < 4; ++m)
        #pragma unroll
        for (int n = 0; n < 4; ++n)
          acc[m][n] = __builtin_amdgcn_mfma_f32_16x16x32_bf16(a[m], bb[n], acc[m][n], 0, 0, 0);
      __syncthreads();   // auto vmcnt(0)+lgkmcnt(0) drain: next chunk ready, buf reusable
    }

    // ---- epilogue for heads ch*4 .. ch*4+3 (wave pair 2j,2j+1 = head j cols)
    {
      int h = ch * 4 + (w >> 1);
      float n2[4][4], nm[4][4];
      #pragma unroll
      for (int m = 0; m < 4; ++m)
        #pragma unroll
        for (int r = 0; r < 4; ++r) { n2[m][r] = 0.f; nm[m][r] = 0.f; }
      #pragma unroll
      for (int n = 0; n < 4; ++n) {
        int c = (w & 1) * 64 + n * 16 + lr;
        float wv = wvec[h * NCOL + c];
        float bq = bqc[h * NCOL + c];
        #pragma unroll
        for (int m = 0; m < 4; ++m)
          #pragma unroll
          for (int r = 0; r < 4; ++r) {
            float qv = acc[m][n][r] + bq;   // C layout: col=lane&15, row=(lane>>4)*4+r
            n2[m][r] += qv * qv;
            nm[m][r] += qv * wv;
          }
      }
      #pragma unroll
      for (int off = 1; off < 16; off <<= 1)
        #pragma unroll
        for (int m = 0; m < 4; ++m)
          #pragma unroll
          for (int r = 0; r < 4; ++r) {
            n2[m][r] += __shfl_xor(n2[m][r], off);
            nm[m][r] += __shfl_xor(nm[m][r], off);
          }
      if (lr == 0) {
        #pragma unroll
        for (int m = 0; m < 4; ++m)
          #pragma unroll
          for (int r = 0; r < 4; ++r) {
            int row = m * 16 + q * 4 + r;
            partn[w * 64 + row] = n2[m][r];
            partm[w * 64 + row] = nm[m][r];
          }
      }
      __syncthreads();
      if (tid < 64) {
        float mk = (mask[(size_t)b * CS + s0 + tid] != 0) ? 1.0f : 0.0f;
        #pragma unroll
        for (int hl = 0; hl < 4; ++hl) {
          float nn = partn[(2 * hl) * 64 + tid] + partn[(2 * hl + 1) * 64 + tid];
          float mm = partm[(2 * hl) * 64 + tid] + partm[(2 * hl + 1) * 64 + tid];
          float sc = mm / sqrtf(fmaxf(nn, EPSV)) * mk;
          scoresA[(ch * 4 + hl) * 64 + tid] = sc;
          float ts = sc;
          #pragma unroll
          for (int off = 1; off < 64; off <<= 1) ts += __shfl_xor(ts, off);
          if (tid == 0) atomicAdd(&ssum[b * CH + ch * 4 + hl], ts);
        }
      }
      __syncthreads();
    }
  }

  // ---- y pass: y[b,h,d] += sum_row score[h][row] * x_bf16[row][d]
  {
    int d = tid;
    float sreg[CH];
    #pragma unroll
    for (int h = 0; h < CH; ++h) sreg[h] = scoresA[h * 64 + l];
    float yacc[CH];
    #pragma unroll
    for (int h = 0; h < CH; ++h) yacc[h] = 0.f;
    #pragma unroll 4
    for (int row = 0; row < TM; ++row) {
      int byte = row * 1024 + ((d * 2) ^ ((row & 7) << 4));
      float xv = bf2f(*(const unsigned short*)(Xl + byte));
      #pragma unroll
      for (int h = 0; h < CH; ++h) {
        float sc = __uint_as_float(
            __builtin_amdgcn_readlane(__float_as_uint(sreg[h]), row));
        yacc[h] += sc * xv;
      }
    }
    #pragma unroll
    for (int h = 0; h < CH; ++h)
      atomicAdd(&yws[((size_t)b * CH + h) * CD + d], yacc[h]);
  }
}

// ---------------- pooled[b, h*64+v] = y[b,h,:]@Wv[h,:,v] + ssum*bv ----------------
// grid 128 (b*8+h), 256 threads (4 d-quarters x 64 v)
__global__ void cap_pooled(const float* __restrict__ yws, const float* __restrict__ ssum,
                           const float* __restrict__ Wv, const float* __restrict__ bv,
                           float* __restrict__ pooled) {
  int blk = blockIdx.x, t = threadIdx.x;
  int b = blk >> 3, h = blk & 7;
  int v = t & 63, dq = t >> 6;
  const float* y = yws + ((size_t)b * CH + h) * CD;
  const float* wv = Wv + (size_t)h * CD * CK;
  float acc = 0.f;
  #pragma unroll 8
  for (int i = 0; i < 128; ++i) {
    int d = i * 4 + dq;
    acc += y[d] * wv[(size_t)d * CK + v];
  }
  __shared__ float red[4][64];
  red[dq][v] = acc;
  __syncthreads();
  if (t < 64) {
    float s = red[0][t] + red[1][t] + red[2][t] + red[3][t] +
              ssum[b * CH + h] * bv[h * CK + t];
    pooled[(size_t)b * 512 + h * 64 + t] = s;
  }
}

// ---------------- out[b, dout] = pooled[b,:]@Wf[:,dout] + bf ----------------
// grid 128 (b*8+dchunk), 256 threads (4 j-quarters x 64 d)
__global__ void cap_out(const float* __restrict__ pooled, const float* __restrict__ Wf,
                        const float* __restrict__ bfv, float* __restrict__ out) {
  int blk = blockIdx.x, t = threadIdx.x;
  int b = blk >> 3, dc = blk & 7;
  int dl = t & 63, jq = t >> 6;
  int dout = dc * 64 + dl;
  const float* pr = pooled + (size_t)b * 512;
  float acc = 0.f;
  #pragma unroll 8
  for (int i = 0; i < 128; ++i) {
    int j = i * 4 + jq;
    acc += pr[j] * Wf[(size_t)j * CD + dout];
  }
  __shared__ float red[4][64];
  red[jq][dl] = acc;
  __syncthreads();
  if (t < 64)
    out[(size_t)b * CD + dc * 64 + t] =
        red[0][t] + red[1][t] + red[2][t] + red[3][t] + bfv[dc * 64 + t];
}

extern "C" void kernel_launch(void* const* d_in, const int* in_sizes, int n_in,
                              void* d_out, int out_size, void* d_ws, size_t ws_size,
                              hipStream_t stream) {
  const float* x = (const float*)d_in[0];
  const int* mask = (const int*)d_in[1];   // bool staged as int32
  const float* Wq_r = (const float*)d_in[2];
  const float* bq_r = (const float*)d_in[3];
  const float* Wq_i = (const float*)d_in[4];
  const float* bq_i = (const float*)d_in[5];
  const float* Wv = (const float*)d_in[6];
  const float* bv = (const float*)d_in[7];
  const float* key_real = (const float*)d_in[8];
  const float* key_imag = (const float*)d_in[9];
  const float* Wf = (const float*)d_in[10];
  const float* bfv = (const float*)d_in[11];
  float* out = (float*)d_out;

  char* ws = (char*)d_ws;
  unsigned short* wbt = (unsigned short*)ws;                         // 1 MB
  float* wvec = (float*)(ws + (1 << 20));                            // 4 KB
  float* bqc  = (float*)(ws + (1 << 20) + 4096);                     // 4 KB
  float* yws  = (float*)(ws + (1 << 20) + 8192);                     // 256 KB
  float* ssum = (float*)(ws + (1 << 20) + 8192 + CB * CH * CD * 4);  // 512 B
  float* pooled = (float*)(ws + (1 << 20) + 8192 + CB * CH * CD * 4 + 512);  // 32 KB

  hipMemsetAsync(yws, 0, CB * CH * CD * 4 + CB * CH * 4, stream);
  cap_prep<<<dim3(128), dim3(256), 0, stream>>>(Wq_r, Wq_i, wbt);
  cap_keys<<<dim3(8), dim3(128), 0, stream>>>(key_real, key_imag, bq_r, bq_i, wvec, bqc);
  hipFuncSetAttribute((const void*)cap_main,
                      hipFuncAttributeMaxDynamicSharedMemorySize, SMEM_BYTES);
  cap_main<<<dim3(CB * (CS / TM)), dim3(512), SMEM_BYTES, stream>>>(
      x, mask, wbt, wvec, bqc, yws, ssum);
  cap_pooled<<<dim3(128), dim3(256), 0, stream>>>(yws, ssum, Wv, bv, pooled);
  cap_out<<<dim3(128), dim3(256), 0, stream>>>(pooled, Wf, bfv, out);
}